// Round 9
// baseline (8797.021 us; speedup 1.0000x reference)
//
#include <hip/hip_runtime.h>

#define HID   1024
#define TLEN  512
#define VOC   128
#define NBLK  256         // = #CUs; 1 block/CU (132KB LDS) -> all co-resident
#define NW    32          // worker team: all blocks of one XCD
#define NO    2           // out-head blocks: 64 vocab cols each
#define LDSK  1032        // padded LDS row stride
#define HBUF  (64 * HID)  // one h buffer (elements)
#define OD    16          // out-ring depth

typedef __bf16 bf16_t;
typedef __attribute__((ext_vector_type(8))) __bf16 bf16x8;
typedef __attribute__((ext_vector_type(4))) float  f32x4;
typedef __attribute__((ext_vector_type(2))) float  f32x2;
typedef __attribute__((ext_vector_type(4))) unsigned uint4v;

__device__ __forceinline__ float sigmoid_fast(float x) {
  return 1.0f / (1.0f + __expf(-x));
}
__device__ __forceinline__ float tanh_fast(float x) {
  float e = __expf(-2.0f * x);
  return (1.0f - e) / (1.0f + e);
}

union PairU { bf16_t b[2]; unsigned u; };

// L1-only invalidate (no sc bits): local to this CU, no fabric traffic.
__device__ __forceinline__ void l1_inv() {
  asm volatile("buffer_inv" ::: "memory");
}

// cross-XCD path (h -> out-heads only): sc1 write-around stores, NT reads.
__device__ __forceinline__ void st_sc1(bf16_t* p, float f0, float f1) {
  PairU c; c.b[0] = (bf16_t)f0; c.b[1] = (bf16_t)f1;
  __hip_atomic_store((unsigned*)p, c.u, __ATOMIC_RELAXED, __HIP_MEMORY_SCOPE_AGENT);
}
__device__ __forceinline__ bf16x8 ld_nt16(const bf16_t* p) {
  union { uint4v u; bf16x8 b; } c;
  c.u = __builtin_nontemporal_load((const uint4v*)p);
  return c.b;
}

// HOT-SPIN polls (no s_sleep: sleeping waves invite clock-gating/DVFS-down).
__device__ __forceinline__ void poll(const unsigned* flags, int n, unsigned tgt) {
  if ((threadIdx.x >> 6) == 0) {
    const int lane = threadIdx.x & 63;
    for (;;) {
      unsigned g = tgt;
      if (lane < n)
        g = __hip_atomic_load(&flags[lane], __ATOMIC_RELAXED, __HIP_MEMORY_SCOPE_AGENT);
      if (__all(g >= tgt)) break;
    }
  }
  __syncthreads();
}

__device__ __forceinline__ void poll_rf_of(const unsigned* rfl, const unsigned* ofl,
                                           unsigned tgt, unsigned otgt) {
  if ((threadIdx.x >> 6) == 0) {
    const int lane = threadIdx.x & 63;
    for (;;) {
      bool ok = true;
      if (lane < NW)
        ok = __hip_atomic_load(&rfl[lane], __ATOMIC_RELAXED, __HIP_MEMORY_SCOPE_AGENT) >= tgt;
      else if (lane < NW + NO)
        ok = __hip_atomic_load(&ofl[lane - NW], __ATOMIC_RELAXED, __HIP_MEMORY_SCOPE_AGENT) >= otgt;
      if (__all(ok)) break;
    }
  }
  __syncthreads();
}

__device__ __forceinline__ void publish(unsigned* f, unsigned v) {
  __syncthreads();
  if (threadIdx.x == 0)
    __hip_atomic_store(f, v, __ATOMIC_RELAXED, __HIP_MEMORY_SCOPE_AGENT);
}

#define MFMA(a, b, c) __builtin_amdgcn_mfma_f32_16x16x32_bf16((a), (b), (c), 0, 0, 0)

__global__ void __launch_bounds__(256, 1)
gru_dvfs(const int* __restrict__ X,
         const float* __restrict__ Wr_x, const float* __restrict__ Wr_h, const float* __restrict__ b_r,
         const float* __restrict__ Wz_x, const float* __restrict__ Wz_h, const float* __restrict__ b_z,
         const float* __restrict__ Wh_x, const float* __restrict__ Wh_h, const float* __restrict__ b_h,
         const float* __restrict__ W_o,  const float* __restrict__ b_o,
         float* __restrict__ out,
         bf16_t* __restrict__ hring, bf16_t* __restrict__ rh_bf,
         bf16_t* __restrict__ oring, bf16_t* __restrict__ wz_bf,
         unsigned* __restrict__ flags)
{
  __shared__ __align__(16) bf16_t Wbuf[2 * 32 * LDSK];  // 132KB
  __shared__ int s_role;

  unsigned* hfl    = flags;        // [0,32)   h slots published (count)
  unsigned* rfl    = flags + 64;   // [64,96)  rh(t) published
  unsigned* ofl    = flags + 128;  // [128,130) out-head progress
  unsigned* cnt    = flags + 192;  // [192,200) per-XCD claim counters
  unsigned* winner = flags + 200;  // 0 = unset, else xcd+1
  unsigned* ocnt   = flags + 204;  // out-head claim counter
  unsigned* done   = flags + 208;  // burner exit flag

  const int tid  = threadIdx.x;
  const int lane = tid & 63;
  const int wv   = tid >> 6;
  const int n16  = lane & 15;
  const int q    = lane >> 4;
  const int aoff = (wv * 16 + n16) * HID + q * 8;

  int bi[4];
#pragma unroll
  for (int i = 0; i < 4; ++i) bi[i] = wv * 16 + q * 4 + i;

  // ---------- self-organize: first XCD to seat 32 blocks = worker team ------
  if (tid == 0) {
    unsigned xcc;
    asm volatile("s_getreg_b32 %0, hwreg(HW_REG_XCC_ID)" : "=s"(xcc));
    xcc &= 7u;
    unsigned idx = __hip_atomic_fetch_add(&cnt[xcc], 1u, __ATOMIC_RELAXED, __HIP_MEMORY_SCOPE_AGENT);
    if (idx == NW - 1) {
      unsigned exp = 0u;
      __hip_atomic_compare_exchange_strong(winner, &exp, xcc + 1u,
          __ATOMIC_RELAXED, __ATOMIC_RELAXED, __HIP_MEMORY_SCOPE_AGENT);
    }
    unsigned w;
    do {
      w = __hip_atomic_load(winner, __ATOMIC_RELAXED, __HIP_MEMORY_SCOPE_AGENT);
    } while (w == 0u);   // guaranteed: 256 blocks over 8 XCDs -> some XCD hits 32
    if (xcc == w - 1u && idx < NW) {
      s_role = (int)idx;
    } else {
      unsigned o = __hip_atomic_fetch_add(ocnt, 1u, __ATOMIC_RELAXED, __HIP_MEMORY_SCOPE_AGENT);
      s_role = (o < NO) ? (NW + (int)o) : -1;
    }
  }
  __syncthreads();
  const int role = s_role;

  if (role < 0) {
    // ============ clock-keeper burner: hold boost clocks for the governor ===
    // Pure VALU (dependent FMA chain), no memory traffic; checks done-flag
    // every ~7us. Without this, 99% idleness drops gfx clock ~4x (the r4-r8
    // invariant 8.5ms floor).
    float a = 1.0f + (float)tid;
    for (;;) {
#pragma unroll 32
      for (int it = 0; it < 4096; ++it)
        a = __builtin_fmaf(a, 0.999999f, 1.0e-7f);
      if (__hip_atomic_load(done, __ATOMIC_RELAXED, __HIP_MEMORY_SCOPE_AGENT) != 0u)
        break;
    }
    if (a == 0.123456789f)  // never true; defeats dead-code elimination
      __hip_atomic_store(flags + 240, 1u, __ATOMIC_RELAXED, __HIP_MEMORY_SCOPE_AGENT);
    return;
  }

  if (role < NW) {
    // ============ worker (winning XCD): 32 cols of r, z, h_tilde ==========
    const int s  = role;
    const int c0 = s * 32;
    for (int idx = tid; idx < 32 * HID; idx += 256) {
      int n = idx & 31, k = idx >> 5;
      int r = (n & 1) * 16 + (n >> 1);
      Wbuf[r * LDSK + k]             = (bf16_t)Wr_h[k * HID + c0 + n];
      Wbuf[32 * LDSK + r * LDSK + k] = (bf16_t)Wh_h[k * HID + c0 + n];
    }
    bf16_t* wzs = wz_bf + s * (32 * 1024);
    for (int idx = tid; idx < 32 * HID; idx += 256) {
      int n = idx & 31, k = idx >> 5;
      int r = (n & 1) * 16 + (n >> 1);
      wzs[r * 1024 + k] = (bf16_t)Wz_h[k * HID + c0 + n];
    }

    const int j0 = c0 + 2 * n16;
#pragma unroll
    for (int i = 0; i < 4; ++i) {
      PairU zz; zz.b[0] = (bf16_t)0.f; zz.b[1] = (bf16_t)0.f;
      *reinterpret_cast<PairU*>(hring + bi[i] * HID + j0) = zz;
    }
    publish(&hfl[s], 1u);   // h slot 0 ready (barrier also covers LDS staging)

    const float br0 = b_r[j0], br1 = b_r[j0 + 1];
    const float bz0 = b_z[j0], bz1 = b_z[j0 + 1];
    const float bh0 = b_h[j0], bh1 = b_h[j0 + 1];
    const bf16_t* wr0 = &Wbuf[n16 * LDSK + q * 8];
    const bf16_t* wr1 = &Wbuf[(16 + n16) * LDSK + q * 8];
    const bf16_t* wh0 = &Wbuf[32 * LDSK + n16 * LDSK + q * 8];
    const bf16_t* wh1 = &Wbuf[32 * LDSK + (16 + n16) * LDSK + q * 8];
    const bf16_t* wz0 = wzs + n16 * 1024 + q * 8;
    const bf16_t* wz1 = wzs + (16 + n16) * 1024 + q * 8;
    const bf16_t* rhrow = rh_bf + aoff;

    f32x4 hm0 = {0.f,0.f,0.f,0.f}, hm1 = {0.f,0.f,0.f,0.f};  // fp32 h master

    for (int t = 0; t < TLEN; ++t) {
      float gr0[4], gr1[4], gz0[4], gz1[4], gh0[4], gh1[4];
#pragma unroll
      for (int i = 0; i < 4; ++i) {
        int xb = X[bi[i] * TLEN + t];
        gr0[i] = Wr_x[xb * HID + j0]; gr1[i] = Wr_x[xb * HID + j0 + 1];
        gz0[i] = Wz_x[xb * HID + j0]; gz1[i] = Wz_x[xb * HID + j0 + 1];
        gh0[i] = Wh_x[xb * HID + j0]; gh1[i] = Wh_x[xb * HID + j0 + 1];
      }
      // ---- r phase ----
      poll(hfl, NW, (unsigned)(t + 1));
      l1_inv();
      const bf16_t* hslot = hring + (t & 1) * HBUF;
      const bf16_t* hrow  = hslot + aoff;
      bf16x8 areg[32];
#pragma unroll
      for (int kk = 0; kk < 32; ++kk)
        areg[kk] = *reinterpret_cast<const bf16x8*>(hrow + kk * 32);
      f32x4 aR0 = {0.f,0.f,0.f,0.f}, aR1 = {0.f,0.f,0.f,0.f};
#pragma unroll
      for (int kk = 0; kk < 32; ++kk) {
        bf16x8 w0 = *reinterpret_cast<const bf16x8*>(wr0 + kk * 32);
        bf16x8 w1 = *reinterpret_cast<const bf16x8*>(wr1 + kk * 32);
        aR0 = MFMA(areg[kk], w0, aR0);
        aR1 = MFMA(areg[kk], w1, aR1);
      }
#pragma unroll
      for (int i = 0; i < 4; ++i) {
        float r0 = sigmoid_fast(aR0[i] + br0 + gr0[i]);
        float r1 = sigmoid_fast(aR1[i] + br1 + gr1[i]);
        PairU hp = *reinterpret_cast<const PairU*>(hslot + bi[i] * HID + j0);
        PairU c;
        c.b[0] = (bf16_t)(r0 * (float)hp.b[0]);
        c.b[1] = (bf16_t)(r1 * (float)hp.b[1]);
        *reinterpret_cast<PairU*>(rh_bf + bi[i] * HID + j0) = c;  // cached, local L2
      }
      publish(&rfl[s], (unsigned)(t + 1));

      // ---- z phase (shadow; reuses areg, streams wz from local L2) ----
      f32x4 aZ0 = {0.f,0.f,0.f,0.f}, aZ1 = {0.f,0.f,0.f,0.f};
#pragma unroll
      for (int kk = 0; kk < 32; ++kk) {
        bf16x8 w0 = *reinterpret_cast<const bf16x8*>(wz0 + kk * 32);
        bf16x8 w1 = *reinterpret_cast<const bf16x8*>(wz1 + kk * 32);
        aZ0 = MFMA(areg[kk], w0, aZ0);
        aZ1 = MFMA(areg[kk], w1, aZ1);
      }
      f32x4 z0, z1;
#pragma unroll
      for (int i = 0; i < 4; ++i) {
        z0[i] = sigmoid_fast(aZ0[i] + bz0 + gz0[i]);
        z1[i] = sigmoid_fast(aZ1[i] + bz1 + gz1[i]);
      }

      // ---- h_tilde phase ----
      unsigned otgt = (t > OD - 1) ? (unsigned)(t + 1 - OD) : 0u;  // oring WAR
      poll_rf_of(rfl, ofl, (unsigned)(t + 1), otgt);
      l1_inv();
      bf16x8 breg[32];
#pragma unroll
      for (int kk = 0; kk < 32; ++kk)
        breg[kk] = *reinterpret_cast<const bf16x8*>(rhrow + kk * 32);
      f32x4 aH0 = {0.f,0.f,0.f,0.f}, aH1 = {0.f,0.f,0.f,0.f};
#pragma unroll
      for (int kk = 0; kk < 32; ++kk) {
        bf16x8 w0 = *reinterpret_cast<const bf16x8*>(wh0 + kk * 32);
        bf16x8 w1 = *reinterpret_cast<const bf16x8*>(wh1 + kk * 32);
        aH0 = MFMA(breg[kk], w0, aH0);
        aH1 = MFMA(breg[kk], w1, aH1);
      }
      bf16_t* hnext = hring + ((t + 1) & 1) * HBUF;
      bf16_t* onext = oring + ((t + 1) % OD) * HBUF;
#pragma unroll
      for (int i = 0; i < 4; ++i) {
        float ht0 = tanh_fast(aH0[i] + bh0 + gh0[i]);
        float ht1 = tanh_fast(aH1[i] + bh1 + gh1[i]);
        float hn0 = z0[i] * hm0[i] + (1.f - z0[i]) * ht0;
        float hn1 = z1[i] * hm1[i] + (1.f - z1[i]) * ht1;
        hm0[i] = hn0; hm1[i] = hn1;
        PairU c; c.b[0] = (bf16_t)hn0; c.b[1] = (bf16_t)hn1;
        *reinterpret_cast<PairU*>(hnext + bi[i] * HID + j0) = c;  // local L2
        st_sc1(onext + bi[i] * HID + j0, hn0, hn1);               // MALL (out path)
      }
      publish(&hfl[s], (unsigned)(t + 2));
    }
    // write back dirty L2 so next replay (possibly different winner XCD)
    // never races two dirty copies at the MALL.
    __builtin_amdgcn_fence(__ATOMIC_RELEASE, "agent");
  } else {
    // ============ out head: 64 vocab cols; out[t-1] = h_t @ W_o + b_o ======
    const int ob  = role - NW;
    const int c0o = ob * 64;
    for (int idx = tid; idx < 64 * HID; idx += 256) {
      int n = idx & 63, k = idx >> 6;
      int g = n >> 5, m = n & 31;
      int r = g * 32 + (m & 1) * 16 + (m >> 1);
      Wbuf[r * LDSK + k] = (bf16_t)W_o[k * VOC + c0o + n];
    }
    __syncthreads();

    float bo[2][2];
#pragma unroll
    for (int g = 0; g < 2; ++g) {
      bo[g][0] = b_o[c0o + 32 * g + 2 * n16];
      bo[g][1] = b_o[c0o + 32 * g + 2 * n16 + 1];
    }
    const bf16_t* wo[2][2];
#pragma unroll
    for (int g = 0; g < 2; ++g)
#pragma unroll
      for (int h = 0; h < 2; ++h)
        wo[g][h] = &Wbuf[(g * 32 + h * 16 + n16) * LDSK + q * 8];

    for (int t = 1; t <= TLEN; ++t) {
      poll(hfl, NW, (unsigned)(t + 1));   // h slot t in the out-ring
      const bf16_t* hrow = oring + (t % OD) * HBUF + aoff;
      bf16x8 areg[32];
#pragma unroll
      for (int kk = 0; kk < 32; ++kk)
        areg[kk] = ld_nt16(hrow + kk * 32);
      f32x4 acc[2][2];
#pragma unroll
      for (int g = 0; g < 2; ++g)
#pragma unroll
        for (int h = 0; h < 2; ++h)
          acc[g][h] = (f32x4){0.f, 0.f, 0.f, 0.f};
#pragma unroll
      for (int kk = 0; kk < 32; ++kk) {
#pragma unroll
        for (int g = 0; g < 2; ++g) {
          bf16x8 w0 = *reinterpret_cast<const bf16x8*>(wo[g][0] + kk * 32);
          bf16x8 w1 = *reinterpret_cast<const bf16x8*>(wo[g][1] + kk * 32);
          acc[g][0] = MFMA(areg[kk], w0, acc[g][0]);
          acc[g][1] = MFMA(areg[kk], w1, acc[g][1]);
        }
      }
#pragma unroll
      for (int g = 0; g < 2; ++g) {
        const int j0 = c0o + 32 * g + 2 * n16;
#pragma unroll
        for (int i = 0; i < 4; ++i) {
          f32x2 v = {acc[g][0][i] + bo[g][0], acc[g][1][i] + bo[g][1]};
          *reinterpret_cast<f32x2*>(&out[(bi[i] * TLEN + (t - 1)) * VOC + j0]) = v;
        }
      }
      publish(&ofl[ob], (unsigned)t);  // NT reads retired (consumed by MFMA)
    }
    if (ob == 0 && tid == 0)  // out-heads finish last -> release the burners
      __hip_atomic_store(done, 1u, __ATOMIC_RELAXED, __HIP_MEMORY_SCOPE_AGENT);
  }
}

extern "C" void kernel_launch(void* const* d_in, const int* in_sizes, int n_in,
                              void* d_out, int out_size, void* d_ws, size_t ws_size,
                              hipStream_t stream) {
  const int*   X    = (const int*)d_in[0];
  const float* Wr_x = (const float*)d_in[1];
  const float* Wr_h = (const float*)d_in[2];
  const float* b_r  = (const float*)d_in[3];
  const float* Wz_x = (const float*)d_in[4];
  const float* Wz_h = (const float*)d_in[5];
  const float* b_z  = (const float*)d_in[6];
  const float* Wh_x = (const float*)d_in[7];
  const float* Wh_h = (const float*)d_in[8];
  const float* b_h  = (const float*)d_in[9];
  const float* W_o  = (const float*)d_in[10];
  const float* b_o  = (const float*)d_in[11];

  char* ws = (char*)d_ws;
  // layout: [flags 4KB | hring 2x128KB | rh 128KB | oring 16x128KB | wz 2MB]
  unsigned* flags = (unsigned*)ws;
  bf16_t*   hring = (bf16_t*)(ws + 4096);
  bf16_t*   rh_bf = (bf16_t*)(ws + 4096 + 2 * HBUF * sizeof(bf16_t));
  bf16_t*   oring = (bf16_t*)(ws + 4096 + 3 * HBUF * sizeof(bf16_t));
  bf16_t*   wz_bf = (bf16_t*)(ws + 4096 + (3 + OD) * HBUF * sizeof(bf16_t));

  // zero flags + claim state; all data buffers are written before read
  hipMemsetAsync(ws, 0, 4096, stream);

  gru_dvfs<<<NBLK, 256, 0, stream>>>(
      X, Wr_x, Wr_h, b_r, Wz_x, Wz_h, b_z, Wh_x, Wh_h, b_h, W_o, b_o,
      (float*)d_out, hring, rh_bf, oring, wz_bf, flags);
}

// Round 10
// 8706.272 us; speedup vs baseline: 1.0104x; 1.0104x over previous
//
#include <hip/hip_runtime.h>

#define HID   1024
#define TLEN  512
#define VOC   128
#define NBLK  256         // = #CUs; 1 block/CU (132KB LDS) -> all co-resident
#define NW    32          // worker team: all blocks of one XCD
#define NO    2           // out-head blocks: 64 vocab cols each
#define LDSK  1032        // padded LDS row stride
#define HBUF  (64 * HID)  // one h buffer (elements)
#define OD    16          // out-ring depth

typedef __bf16 bf16_t;
typedef __attribute__((ext_vector_type(8))) __bf16 bf16x8;
typedef __attribute__((ext_vector_type(4))) float  f32x4;
typedef __attribute__((ext_vector_type(2))) float  f32x2;
typedef __attribute__((ext_vector_type(4))) unsigned uint4v;

__device__ __forceinline__ float sigmoid_fast(float x) {
  return 1.0f / (1.0f + __expf(-x));
}
__device__ __forceinline__ float tanh_fast(float x) {
  float e = __expf(-2.0f * x);
  return (1.0f - e) / (1.0f + e);
}

union PairU { bf16_t b[2]; unsigned u; };

// L1-only invalidate (no sc bits): local to this CU, no fabric traffic.
__device__ __forceinline__ void l1_inv() {
  asm volatile("buffer_inv" ::: "memory");
}

// cross-XCD path (h -> out-heads only): sc1 write-around stores, NT reads.
__device__ __forceinline__ void st_sc1(bf16_t* p, float f0, float f1) {
  PairU c; c.b[0] = (bf16_t)f0; c.b[1] = (bf16_t)f1;
  __hip_atomic_store((unsigned*)p, c.u, __ATOMIC_RELAXED, __HIP_MEMORY_SCOPE_AGENT);
}
__device__ __forceinline__ bf16x8 ld_nt16(const bf16_t* p) {
  union { uint4v u; bf16x8 b; } c;
  c.u = __builtin_nontemporal_load((const uint4v*)p);
  return c.b;
}

// BURN-POLL: every wave polls independently (monotone condition -> no barrier)
// and runs a dependent-FMA burn between checks. Keeps this CU's SIMDs
// VALU-busy during the wait so the WINNER XCD's clock governor sees a busy
// XCD (per-XCD gfx clock domains -- r9's remote burners heated only the
// losing XCDs and changed nothing).
__device__ __forceinline__ void burnpoll(const unsigned* flags, int n, unsigned tgt) {
  const int lane = threadIdx.x & 63;
  float a = 1.0f + (float)lane;
  for (;;) {
    unsigned g = tgt;
    if (lane < n)
      g = __hip_atomic_load(&flags[lane], __ATOMIC_RELAXED, __HIP_MEMORY_SCOPE_AGENT);
    if (__all(g >= tgt)) break;
#pragma unroll
    for (int it = 0; it < 128; ++it)
      a = __builtin_fmaf(a, 0.99999988f, 1.1920929e-7f);
  }
  asm volatile("" :: "v"(a));  // keep the burn alive (defeat DCE)
}

// rfl[0..NW) >= tgt AND ofl[0..NO) >= otgt, burn-polled by every wave.
__device__ __forceinline__ void burnpoll_rf_of(const unsigned* rfl, const unsigned* ofl,
                                               unsigned tgt, unsigned otgt) {
  const int lane = threadIdx.x & 63;
  float a = 1.0f + (float)lane;
  for (;;) {
    bool ok = true;
    if (lane < NW)
      ok = __hip_atomic_load(&rfl[lane], __ATOMIC_RELAXED, __HIP_MEMORY_SCOPE_AGENT) >= tgt;
    else if (lane < NW + NO)
      ok = __hip_atomic_load(&ofl[lane - NW], __ATOMIC_RELAXED, __HIP_MEMORY_SCOPE_AGENT) >= otgt;
    if (__all(ok)) break;
#pragma unroll
    for (int it = 0; it < 128; ++it)
      a = __builtin_fmaf(a, 0.99999988f, 1.1920929e-7f);
  }
  asm volatile("" :: "v"(a));
}

__device__ __forceinline__ void publish(unsigned* f, unsigned v) {
  __syncthreads();   // drains all waves' stores (vmcnt(0) before s_barrier)
  if (threadIdx.x == 0)
    __hip_atomic_store(f, v, __ATOMIC_RELAXED, __HIP_MEMORY_SCOPE_AGENT);
}

#define MFMA(a, b, c) __builtin_amdgcn_mfma_f32_16x16x32_bf16((a), (b), (c), 0, 0, 0)

__global__ void __launch_bounds__(256, 1)
gru_burn(const int* __restrict__ X,
         const float* __restrict__ Wr_x, const float* __restrict__ Wr_h, const float* __restrict__ b_r,
         const float* __restrict__ Wz_x, const float* __restrict__ Wz_h, const float* __restrict__ b_z,
         const float* __restrict__ Wh_x, const float* __restrict__ Wh_h, const float* __restrict__ b_h,
         const float* __restrict__ W_o,  const float* __restrict__ b_o,
         float* __restrict__ out,
         bf16_t* __restrict__ hring, bf16_t* __restrict__ rh_bf,
         bf16_t* __restrict__ oring, bf16_t* __restrict__ wz_bf,
         unsigned* __restrict__ flags)
{
  __shared__ __align__(16) bf16_t Wbuf[2 * 32 * LDSK];  // 132KB
  __shared__ int s_role;

  unsigned* hfl    = flags;        // [0,32)   h slots published (count)
  unsigned* rfl    = flags + 64;   // [64,96)  rh(t) published
  unsigned* ofl    = flags + 128;  // [128,130) out-head progress
  unsigned* cnt    = flags + 192;  // [192,200) per-XCD claim counters
  unsigned* winner = flags + 200;  // 0 = unset, else xcd+1
  unsigned* ocnt   = flags + 204;  // out-head claim counter
  unsigned* done   = flags + 208;  // burner exit flag

  const int tid  = threadIdx.x;
  const int lane = tid & 63;
  const int wv   = tid >> 6;
  const int n16  = lane & 15;
  const int q    = lane >> 4;
  const int aoff = (wv * 16 + n16) * HID + q * 8;

  int bi[4];
#pragma unroll
  for (int i = 0; i < 4; ++i) bi[i] = wv * 16 + q * 4 + i;

  // ---------- self-organize: first XCD to seat 32 blocks = worker team ------
  if (tid == 0) {
    unsigned xcc;
    asm volatile("s_getreg_b32 %0, hwreg(HW_REG_XCC_ID)" : "=s"(xcc));
    xcc &= 7u;
    unsigned idx = __hip_atomic_fetch_add(&cnt[xcc], 1u, __ATOMIC_RELAXED, __HIP_MEMORY_SCOPE_AGENT);
    if (idx == NW - 1) {
      unsigned exp = 0u;
      __hip_atomic_compare_exchange_strong(winner, &exp, xcc + 1u,
          __ATOMIC_RELAXED, __ATOMIC_RELAXED, __HIP_MEMORY_SCOPE_AGENT);
    }
    unsigned w;
    do {
      w = __hip_atomic_load(winner, __ATOMIC_RELAXED, __HIP_MEMORY_SCOPE_AGENT);
    } while (w == 0u);   // guaranteed: 256 blocks over 8 XCDs -> some XCD hits 32
    if (xcc == w - 1u && idx < NW) {
      s_role = (int)idx;
    } else {
      unsigned o = __hip_atomic_fetch_add(ocnt, 1u, __ATOMIC_RELAXED, __HIP_MEMORY_SCOPE_AGENT);
      s_role = (o < NO) ? (NW + (int)o) : -1;
    }
  }
  __syncthreads();
  const int role = s_role;

  if (role < 0) {
    // ===== losing-XCD burners: keep the non-critical XCDs (oring/out path) hot
    float a = 1.0f + (float)tid;
    for (;;) {
#pragma unroll 32
      for (int it = 0; it < 4096; ++it)
        a = __builtin_fmaf(a, 0.999999f, 1.0e-7f);
      if (__hip_atomic_load(done, __ATOMIC_RELAXED, __HIP_MEMORY_SCOPE_AGENT) != 0u)
        break;
    }
    asm volatile("" :: "v"(a));
    return;
  }

  if (role < NW) {
    // ============ worker (winning XCD): 32 cols of r, z, h_tilde ==========
    const int s  = role;
    const int c0 = s * 32;
    for (int idx = tid; idx < 32 * HID; idx += 256) {
      int n = idx & 31, k = idx >> 5;
      int r = (n & 1) * 16 + (n >> 1);
      Wbuf[r * LDSK + k]             = (bf16_t)Wr_h[k * HID + c0 + n];
      Wbuf[32 * LDSK + r * LDSK + k] = (bf16_t)Wh_h[k * HID + c0 + n];
    }
    bf16_t* wzs = wz_bf + s * (32 * 1024);
    for (int idx = tid; idx < 32 * HID; idx += 256) {
      int n = idx & 31, k = idx >> 5;
      int r = (n & 1) * 16 + (n >> 1);
      wzs[r * 1024 + k] = (bf16_t)Wz_h[k * HID + c0 + n];
    }

    const int j0 = c0 + 2 * n16;
#pragma unroll
    for (int i = 0; i < 4; ++i) {
      PairU zz; zz.b[0] = (bf16_t)0.f; zz.b[1] = (bf16_t)0.f;
      *reinterpret_cast<PairU*>(hring + bi[i] * HID + j0) = zz;
    }
    publish(&hfl[s], 1u);   // h slot 0 ready (barrier also covers LDS staging)

    const float br0 = b_r[j0], br1 = b_r[j0 + 1];
    const float bz0 = b_z[j0], bz1 = b_z[j0 + 1];
    const float bh0 = b_h[j0], bh1 = b_h[j0 + 1];
    const bf16_t* wr0 = &Wbuf[n16 * LDSK + q * 8];
    const bf16_t* wr1 = &Wbuf[(16 + n16) * LDSK + q * 8];
    const bf16_t* wh0 = &Wbuf[32 * LDSK + n16 * LDSK + q * 8];
    const bf16_t* wh1 = &Wbuf[32 * LDSK + (16 + n16) * LDSK + q * 8];
    const bf16_t* wz0 = wzs + n16 * 1024 + q * 8;
    const bf16_t* wz1 = wzs + (16 + n16) * 1024 + q * 8;
    const bf16_t* rhrow = rh_bf + aoff;

    f32x4 hm0 = {0.f,0.f,0.f,0.f}, hm1 = {0.f,0.f,0.f,0.f};  // fp32 h master

    for (int t = 0; t < TLEN; ++t) {
      float gr0[4], gr1[4], gz0[4], gz1[4], gh0[4], gh1[4];
#pragma unroll
      for (int i = 0; i < 4; ++i) {
        int xb = X[bi[i] * TLEN + t];
        gr0[i] = Wr_x[xb * HID + j0]; gr1[i] = Wr_x[xb * HID + j0 + 1];
        gz0[i] = Wz_x[xb * HID + j0]; gz1[i] = Wz_x[xb * HID + j0 + 1];
        gh0[i] = Wh_x[xb * HID + j0]; gh1[i] = Wh_x[xb * HID + j0 + 1];
      }
      // ---- r phase ----
      burnpoll(hfl, NW, (unsigned)(t + 1));
      l1_inv();
      const bf16_t* hslot = hring + (t & 1) * HBUF;
      const bf16_t* hrow  = hslot + aoff;
      bf16x8 areg[32];
#pragma unroll
      for (int kk = 0; kk < 32; ++kk)
        areg[kk] = *reinterpret_cast<const bf16x8*>(hrow + kk * 32);
      f32x4 aR0 = {0.f,0.f,0.f,0.f}, aR1 = {0.f,0.f,0.f,0.f};
#pragma unroll
      for (int kk = 0; kk < 32; ++kk) {
        bf16x8 w0 = *reinterpret_cast<const bf16x8*>(wr0 + kk * 32);
        bf16x8 w1 = *reinterpret_cast<const bf16x8*>(wr1 + kk * 32);
        aR0 = MFMA(areg[kk], w0, aR0);
        aR1 = MFMA(areg[kk], w1, aR1);
      }
#pragma unroll
      for (int i = 0; i < 4; ++i) {
        float r0 = sigmoid_fast(aR0[i] + br0 + gr0[i]);
        float r1 = sigmoid_fast(aR1[i] + br1 + gr1[i]);
        PairU hp = *reinterpret_cast<const PairU*>(hslot + bi[i] * HID + j0);
        PairU c;
        c.b[0] = (bf16_t)(r0 * (float)hp.b[0]);
        c.b[1] = (bf16_t)(r1 * (float)hp.b[1]);
        *reinterpret_cast<PairU*>(rh_bf + bi[i] * HID + j0) = c;  // cached, local L2
      }
      publish(&rfl[s], (unsigned)(t + 1));

      // ---- z phase (shadow; reuses areg, streams wz from local L2) ----
      f32x4 aZ0 = {0.f,0.f,0.f,0.f}, aZ1 = {0.f,0.f,0.f,0.f};
#pragma unroll
      for (int kk = 0; kk < 32; ++kk) {
        bf16x8 w0 = *reinterpret_cast<const bf16x8*>(wz0 + kk * 32);
        bf16x8 w1 = *reinterpret_cast<const bf16x8*>(wz1 + kk * 32);
        aZ0 = MFMA(areg[kk], w0, aZ0);
        aZ1 = MFMA(areg[kk], w1, aZ1);
      }
      f32x4 z0, z1;
#pragma unroll
      for (int i = 0; i < 4; ++i) {
        z0[i] = sigmoid_fast(aZ0[i] + bz0 + gz0[i]);
        z1[i] = sigmoid_fast(aZ1[i] + bz1 + gz1[i]);
      }

      // ---- h_tilde phase ----
      unsigned otgt = (t > OD - 1) ? (unsigned)(t + 1 - OD) : 0u;  // oring WAR
      burnpoll_rf_of(rfl, ofl, (unsigned)(t + 1), otgt);
      l1_inv();
      bf16x8 breg[32];
#pragma unroll
      for (int kk = 0; kk < 32; ++kk)
        breg[kk] = *reinterpret_cast<const bf16x8*>(rhrow + kk * 32);
      f32x4 aH0 = {0.f,0.f,0.f,0.f}, aH1 = {0.f,0.f,0.f,0.f};
#pragma unroll
      for (int kk = 0; kk < 32; ++kk) {
        bf16x8 w0 = *reinterpret_cast<const bf16x8*>(wh0 + kk * 32);
        bf16x8 w1 = *reinterpret_cast<const bf16x8*>(wh1 + kk * 32);
        aH0 = MFMA(breg[kk], w0, aH0);
        aH1 = MFMA(breg[kk], w1, aH1);
      }
      bf16_t* hnext = hring + ((t + 1) & 1) * HBUF;
      bf16_t* onext = oring + ((t + 1) % OD) * HBUF;
#pragma unroll
      for (int i = 0; i < 4; ++i) {
        float ht0 = tanh_fast(aH0[i] + bh0 + gh0[i]);
        float ht1 = tanh_fast(aH1[i] + bh1 + gh1[i]);
        float hn0 = z0[i] * hm0[i] + (1.f - z0[i]) * ht0;
        float hn1 = z1[i] * hm1[i] + (1.f - z1[i]) * ht1;
        hm0[i] = hn0; hm1[i] = hn1;
        PairU c; c.b[0] = (bf16_t)hn0; c.b[1] = (bf16_t)hn1;
        *reinterpret_cast<PairU*>(hnext + bi[i] * HID + j0) = c;  // local L2
        st_sc1(onext + bi[i] * HID + j0, hn0, hn1);               // MALL (out path)
      }
      publish(&hfl[s], (unsigned)(t + 2));
    }
    // write back dirty L2 so next replay (possibly different winner XCD)
    // never races two dirty copies at the MALL.
    __builtin_amdgcn_fence(__ATOMIC_RELEASE, "agent");
  } else {
    // ============ out head: 64 vocab cols; out[t-1] = h_t @ W_o + b_o ======
    const int ob  = role - NW;
    const int c0o = ob * 64;
    for (int idx = tid; idx < 64 * HID; idx += 256) {
      int n = idx & 63, k = idx >> 6;
      int g = n >> 5, m = n & 31;
      int r = g * 32 + (m & 1) * 16 + (m >> 1);
      Wbuf[r * LDSK + k] = (bf16_t)W_o[k * VOC + c0o + n];
    }
    __syncthreads();

    float bo[2][2];
#pragma unroll
    for (int g = 0; g < 2; ++g) {
      bo[g][0] = b_o[c0o + 32 * g + 2 * n16];
      bo[g][1] = b_o[c0o + 32 * g + 2 * n16 + 1];
    }
    const bf16_t* wo[2][2];
#pragma unroll
    for (int g = 0; g < 2; ++g)
#pragma unroll
      for (int h = 0; h < 2; ++h)
        wo[g][h] = &Wbuf[(g * 32 + h * 16 + n16) * LDSK + q * 8];

    for (int t = 1; t <= TLEN; ++t) {
      burnpoll(hfl, NW, (unsigned)(t + 1));   // h slot t in the out-ring
      const bf16_t* hrow = oring + (t % OD) * HBUF + aoff;
      bf16x8 areg[32];
#pragma unroll
      for (int kk = 0; kk < 32; ++kk)
        areg[kk] = ld_nt16(hrow + kk * 32);
      f32x4 acc[2][2];
#pragma unroll
      for (int g = 0; g < 2; ++g)
#pragma unroll
        for (int h = 0; h < 2; ++h)
          acc[g][h] = (f32x4){0.f, 0.f, 0.f, 0.f};
#pragma unroll
      for (int kk = 0; kk < 32; ++kk) {
#pragma unroll
        for (int g = 0; g < 2; ++g) {
          bf16x8 w0 = *reinterpret_cast<const bf16x8*>(wo[g][0] + kk * 32);
          bf16x8 w1 = *reinterpret_cast<const bf16x8*>(wo[g][1] + kk * 32);
          acc[g][0] = MFMA(areg[kk], w0, acc[g][0]);
          acc[g][1] = MFMA(areg[kk], w1, acc[g][1]);
        }
      }
#pragma unroll
      for (int g = 0; g < 2; ++g) {
        const int j0 = c0o + 32 * g + 2 * n16;
#pragma unroll
        for (int i = 0; i < 4; ++i) {
          f32x2 v = {acc[g][0][i] + bo[g][0], acc[g][1][i] + bo[g][1]};
          *reinterpret_cast<f32x2*>(&out[(bi[i] * TLEN + (t - 1)) * VOC + j0]) = v;
        }
      }
      publish(&ofl[ob], (unsigned)t);  // NT reads retired (consumed by MFMA)
    }
    if (ob == 0 && tid == 0)  // out-heads finish last -> release the burners
      __hip_atomic_store(done, 1u, __ATOMIC_RELAXED, __HIP_MEMORY_SCOPE_AGENT);
  }
}

extern "C" void kernel_launch(void* const* d_in, const int* in_sizes, int n_in,
                              void* d_out, int out_size, void* d_ws, size_t ws_size,
                              hipStream_t stream) {
  const int*   X    = (const int*)d_in[0];
  const float* Wr_x = (const float*)d_in[1];
  const float* Wr_h = (const float*)d_in[2];
  const float* b_r  = (const float*)d_in[3];
  const float* Wz_x = (const float*)d_in[4];
  const float* Wz_h = (const float*)d_in[5];
  const float* b_z  = (const float*)d_in[6];
  const float* Wh_x = (const float*)d_in[7];
  const float* Wh_h = (const float*)d_in[8];
  const float* b_h  = (const float*)d_in[9];
  const float* W_o  = (const float*)d_in[10];
  const float* b_o  = (const float*)d_in[11];

  char* ws = (char*)d_ws;
  // layout: [flags 4KB | hring 2x128KB | rh 128KB | oring 16x128KB | wz 2MB]
  unsigned* flags = (unsigned*)ws;
  bf16_t*   hring = (bf16_t*)(ws + 4096);
  bf16_t*   rh_bf = (bf16_t*)(ws + 4096 + 2 * HBUF * sizeof(bf16_t));
  bf16_t*   oring = (bf16_t*)(ws + 4096 + 3 * HBUF * sizeof(bf16_t));
  bf16_t*   wz_bf = (bf16_t*)(ws + 4096 + (3 + OD) * HBUF * sizeof(bf16_t));

  // zero flags + claim state; all data buffers are written before read
  hipMemsetAsync(ws, 0, 4096, stream);

  gru_burn<<<NBLK, 256, 0, stream>>>(
      X, Wr_x, Wr_h, b_r, Wz_x, Wz_h, b_z, Wh_x, Wh_h, b_h, W_o, b_o,
      (float*)d_out, hring, rh_bf, oring, wz_bf, flags);
}

// Round 11
// 8425.008 us; speedup vs baseline: 1.0442x; 1.0334x over previous
//
#include <hip/hip_runtime.h>

#define HID   1024
#define TLEN  512
#define VOC   128
#define NBLK  256         // = #CUs; 1 block/CU (132KB LDS) -> all co-resident
#define NW    32          // worker team: all blocks of one XCD
#define NO    2           // out-head blocks: 64 vocab cols each
#define LDSK  1032        // padded LDS row stride
#define HBUF  (64 * HID)  // one h buffer (elements)
#define OD    16          // out-ring depth

typedef __bf16 bf16_t;
typedef __attribute__((ext_vector_type(8))) __bf16 bf16x8;
typedef __attribute__((ext_vector_type(4))) float  f32x4;
typedef __attribute__((ext_vector_type(2))) float  f32x2;
typedef __attribute__((ext_vector_type(4))) unsigned uint4v;

__device__ __forceinline__ float sigmoid_fast(float x) {
  return 1.0f / (1.0f + __expf(-x));
}
__device__ __forceinline__ float tanh_fast(float x) {
  float e = __expf(-2.0f * x);
  return (1.0f - e) / (1.0f + e);
}

union PairU { bf16_t b[2]; unsigned u; };

// L1-only invalidate (no sc bits): local to this CU, no fabric traffic.
__device__ __forceinline__ void l1_inv() {
  asm volatile("buffer_inv" ::: "memory");
}

// cross-XCD path (h -> out-heads only): sc1 write-around stores, NT reads.
__device__ __forceinline__ void st_sc1(bf16_t* p, float f0, float f1) {
  PairU c; c.b[0] = (bf16_t)f0; c.b[1] = (bf16_t)f1;
  __hip_atomic_store((unsigned*)p, c.u, __ATOMIC_RELAXED, __HIP_MEMORY_SCOPE_AGENT);
}
__device__ __forceinline__ bf16x8 ld_nt16(const bf16_t* p) {
  union { uint4v u; bf16x8 b; } c;
  c.u = __builtin_nontemporal_load((const uint4v*)p);
  return c.b;
}

// SINGLE-LANE poll of one aggregate epoch counter. r1-r10 all polled 32-64
// per-producer flags with 64 lanes x ~34 blocks of non-coalescing atomic
// loads -> thousands of serialized same-line transactions at the MALL (the
// invariant 8.5us/hop). One lane, one address: ~34 concurrent pollers total.
__device__ __forceinline__ void wait1(const unsigned* ctr, unsigned tgt) {
  if (threadIdx.x == 0) {
    while (__hip_atomic_load(ctr, __ATOMIC_RELAXED, __HIP_MEMORY_SCOPE_AGENT) < tgt)
      __builtin_amdgcn_s_sleep(1);
  }
  __syncthreads();
}

// combined: rh_ctr >= tgt AND both out-head counters >= otgt (3 lanes, each
// polling its own cacheline).
__device__ __forceinline__ void wait_rh_oc(const unsigned* rctr, const unsigned* oc0,
                                           const unsigned* oc1, unsigned tgt, unsigned otgt) {
  if (threadIdx.x < 64) {
    const int lane = threadIdx.x;
    for (;;) {
      bool ok = true;
      if (lane == 0)      ok = __hip_atomic_load(rctr, __ATOMIC_RELAXED, __HIP_MEMORY_SCOPE_AGENT) >= tgt;
      else if (lane == 1) ok = __hip_atomic_load(oc0,  __ATOMIC_RELAXED, __HIP_MEMORY_SCOPE_AGENT) >= otgt;
      else if (lane == 2) ok = __hip_atomic_load(oc1,  __ATOMIC_RELAXED, __HIP_MEMORY_SCOPE_AGENT) >= otgt;
      if (__all(ok)) break;
      __builtin_amdgcn_s_sleep(1);
    }
  }
  __syncthreads();
}

// arrival: __syncthreads drains this block's stores (vmcnt(0) before s_barrier
// -> cached stores in local L2, sc1 stores at the MALL), then ONE fetch_add.
__device__ __forceinline__ void publish_add(unsigned* ctr) {
  __syncthreads();
  if (threadIdx.x == 0)
    __hip_atomic_fetch_add(ctr, 1u, __ATOMIC_RELAXED, __HIP_MEMORY_SCOPE_AGENT);
}
__device__ __forceinline__ void publish_val(unsigned* f, unsigned v) {
  __syncthreads();
  if (threadIdx.x == 0)
    __hip_atomic_store(f, v, __ATOMIC_RELAXED, __HIP_MEMORY_SCOPE_AGENT);
}

#define MFMA(a, b, c) __builtin_amdgcn_mfma_f32_16x16x32_bf16((a), (b), (c), 0, 0, 0)

__global__ void __launch_bounds__(256, 1)
gru_ctr(const int* __restrict__ X,
        const float* __restrict__ Wr_x, const float* __restrict__ Wr_h, const float* __restrict__ b_r,
        const float* __restrict__ Wz_x, const float* __restrict__ Wz_h, const float* __restrict__ b_z,
        const float* __restrict__ Wh_x, const float* __restrict__ Wh_h, const float* __restrict__ b_h,
        const float* __restrict__ W_o,  const float* __restrict__ b_o,
        float* __restrict__ out,
        bf16_t* __restrict__ hring, bf16_t* __restrict__ rh_bf,
        bf16_t* __restrict__ oring, bf16_t* __restrict__ wz_bf,
        unsigned* __restrict__ flags)
{
  __shared__ __align__(16) bf16_t Wbuf[2 * 32 * LDSK];  // 132KB
  __shared__ int s_role;

  unsigned* h_ctr  = flags;        // line 0: sum of worker h publishes
  unsigned* rh_ctr = flags + 32;   // line 1: sum of worker rh publishes
  unsigned* oc0    = flags + 64;   // line 2: out-head 0 progress (step)
  unsigned* oc1    = flags + 96;   // line 3: out-head 1 progress
  unsigned* cnt    = flags + 128;  // [128,136) per-XCD claim counters
  unsigned* winner = flags + 160;  // 0 = unset, else xcd+1
  unsigned* ocnt   = flags + 164;  // out-head claim counter

  const int tid  = threadIdx.x;
  const int lane = tid & 63;
  const int wv   = tid >> 6;
  const int n16  = lane & 15;
  const int q    = lane >> 4;
  const int aoff = (wv * 16 + n16) * HID + q * 8;

  int bi[4];
#pragma unroll
  for (int i = 0; i < 4; ++i) bi[i] = wv * 16 + q * 4 + i;

  // ---------- self-organize: first XCD to seat 32 blocks = worker team ------
  if (tid == 0) {
    unsigned xcc;
    asm volatile("s_getreg_b32 %0, hwreg(HW_REG_XCC_ID)" : "=s"(xcc));
    xcc &= 7u;
    unsigned idx = __hip_atomic_fetch_add(&cnt[xcc], 1u, __ATOMIC_RELAXED, __HIP_MEMORY_SCOPE_AGENT);
    if (idx == NW - 1) {
      unsigned exp = 0u;
      __hip_atomic_compare_exchange_strong(winner, &exp, xcc + 1u,
          __ATOMIC_RELAXED, __ATOMIC_RELAXED, __HIP_MEMORY_SCOPE_AGENT);
    }
    unsigned w;
    do {
      w = __hip_atomic_load(winner, __ATOMIC_RELAXED, __HIP_MEMORY_SCOPE_AGENT);
      __builtin_amdgcn_s_sleep(1);
    } while (w == 0u);   // guaranteed: 256 blocks over 8 XCDs -> some XCD hits 32
    if (xcc == w - 1u && idx < NW) {
      s_role = (int)idx;
    } else {
      unsigned o = __hip_atomic_fetch_add(ocnt, 1u, __ATOMIC_RELAXED, __HIP_MEMORY_SCOPE_AGENT);
      s_role = (o < NO) ? (NW + (int)o) : -1;
    }
  }
  __syncthreads();
  const int role = s_role;
  if (role < 0) return;

  if (role < NW) {
    // ============ worker (winning XCD): 32 cols of r, z, h_tilde ==========
    const int s  = role;
    const int c0 = s * 32;
    for (int idx = tid; idx < 32 * HID; idx += 256) {
      int n = idx & 31, k = idx >> 5;
      int r = (n & 1) * 16 + (n >> 1);
      Wbuf[r * LDSK + k]             = (bf16_t)Wr_h[k * HID + c0 + n];
      Wbuf[32 * LDSK + r * LDSK + k] = (bf16_t)Wh_h[k * HID + c0 + n];
    }
    bf16_t* wzs = wz_bf + s * (32 * 1024);
    for (int idx = tid; idx < 32 * HID; idx += 256) {
      int n = idx & 31, k = idx >> 5;
      int r = (n & 1) * 16 + (n >> 1);
      wzs[r * 1024 + k] = (bf16_t)Wz_h[k * HID + c0 + n];
    }

    const int j0 = c0 + 2 * n16;
#pragma unroll
    for (int i = 0; i < 4; ++i) {
      PairU zz; zz.b[0] = (bf16_t)0.f; zz.b[1] = (bf16_t)0.f;
      *reinterpret_cast<PairU*>(hring + bi[i] * HID + j0) = zz;
    }
    publish_add(h_ctr);   // h slot 0 ready; h_ctr = 32*(0+1) when all arrive

    const float br0 = b_r[j0], br1 = b_r[j0 + 1];
    const float bz0 = b_z[j0], bz1 = b_z[j0 + 1];
    const float bh0 = b_h[j0], bh1 = b_h[j0 + 1];
    const bf16_t* wr0 = &Wbuf[n16 * LDSK + q * 8];
    const bf16_t* wr1 = &Wbuf[(16 + n16) * LDSK + q * 8];
    const bf16_t* wh0 = &Wbuf[32 * LDSK + n16 * LDSK + q * 8];
    const bf16_t* wh1 = &Wbuf[32 * LDSK + (16 + n16) * LDSK + q * 8];
    const bf16_t* wz0 = wzs + n16 * 1024 + q * 8;
    const bf16_t* wz1 = wzs + (16 + n16) * 1024 + q * 8;
    const bf16_t* rhrow = rh_bf + aoff;

    f32x4 hm0 = {0.f,0.f,0.f,0.f}, hm1 = {0.f,0.f,0.f,0.f};  // fp32 h master

    for (int t = 0; t < TLEN; ++t) {
      float gr0[4], gr1[4], gz0[4], gz1[4], gh0[4], gh1[4];
#pragma unroll
      for (int i = 0; i < 4; ++i) {
        int xb = X[bi[i] * TLEN + t];
        gr0[i] = Wr_x[xb * HID + j0]; gr1[i] = Wr_x[xb * HID + j0 + 1];
        gz0[i] = Wz_x[xb * HID + j0]; gz1[i] = Wz_x[xb * HID + j0 + 1];
        gh0[i] = Wh_x[xb * HID + j0]; gh1[i] = Wh_x[xb * HID + j0 + 1];
      }
      // ---- r phase ----
      wait1(h_ctr, (unsigned)(NW * (t + 1)));
      l1_inv();
      const bf16_t* hslot = hring + (t & 1) * HBUF;
      const bf16_t* hrow  = hslot + aoff;
      bf16x8 areg[32];
#pragma unroll
      for (int kk = 0; kk < 32; ++kk)
        areg[kk] = *reinterpret_cast<const bf16x8*>(hrow + kk * 32);
      f32x4 aR0 = {0.f,0.f,0.f,0.f}, aR1 = {0.f,0.f,0.f,0.f};
#pragma unroll
      for (int kk = 0; kk < 32; ++kk) {
        bf16x8 w0 = *reinterpret_cast<const bf16x8*>(wr0 + kk * 32);
        bf16x8 w1 = *reinterpret_cast<const bf16x8*>(wr1 + kk * 32);
        aR0 = MFMA(areg[kk], w0, aR0);
        aR1 = MFMA(areg[kk], w1, aR1);
      }
#pragma unroll
      for (int i = 0; i < 4; ++i) {
        float r0 = sigmoid_fast(aR0[i] + br0 + gr0[i]);
        float r1 = sigmoid_fast(aR1[i] + br1 + gr1[i]);
        PairU hp = *reinterpret_cast<const PairU*>(hslot + bi[i] * HID + j0);
        PairU c;
        c.b[0] = (bf16_t)(r0 * (float)hp.b[0]);
        c.b[1] = (bf16_t)(r1 * (float)hp.b[1]);
        *reinterpret_cast<PairU*>(rh_bf + bi[i] * HID + j0) = c;  // cached, local L2
      }
      publish_add(rh_ctr);   // rh_ctr -> 32*(t+1)

      // ---- z phase (shadow; reuses areg, streams wz from local L2) ----
      f32x4 aZ0 = {0.f,0.f,0.f,0.f}, aZ1 = {0.f,0.f,0.f,0.f};
#pragma unroll
      for (int kk = 0; kk < 32; ++kk) {
        bf16x8 w0 = *reinterpret_cast<const bf16x8*>(wz0 + kk * 32);
        bf16x8 w1 = *reinterpret_cast<const bf16x8*>(wz1 + kk * 32);
        aZ0 = MFMA(areg[kk], w0, aZ0);
        aZ1 = MFMA(areg[kk], w1, aZ1);
      }
      f32x4 z0, z1;
#pragma unroll
      for (int i = 0; i < 4; ++i) {
        z0[i] = sigmoid_fast(aZ0[i] + bz0 + gz0[i]);
        z1[i] = sigmoid_fast(aZ1[i] + bz1 + gz1[i]);
      }

      // ---- h_tilde phase ----
      unsigned otgt = (t > OD - 1) ? (unsigned)(t + 1 - OD) : 0u;  // oring WAR
      wait_rh_oc(rh_ctr, oc0, oc1, (unsigned)(NW * (t + 1)), otgt);
      l1_inv();
      bf16x8 breg[32];
#pragma unroll
      for (int kk = 0; kk < 32; ++kk)
        breg[kk] = *reinterpret_cast<const bf16x8*>(rhrow + kk * 32);
      f32x4 aH0 = {0.f,0.f,0.f,0.f}, aH1 = {0.f,0.f,0.f,0.f};
#pragma unroll
      for (int kk = 0; kk < 32; ++kk) {
        bf16x8 w0 = *reinterpret_cast<const bf16x8*>(wh0 + kk * 32);
        bf16x8 w1 = *reinterpret_cast<const bf16x8*>(wh1 + kk * 32);
        aH0 = MFMA(breg[kk], w0, aH0);
        aH1 = MFMA(breg[kk], w1, aH1);
      }
      bf16_t* hnext = hring + ((t + 1) & 1) * HBUF;
      bf16_t* onext = oring + ((t + 1) % OD) * HBUF;
#pragma unroll
      for (int i = 0; i < 4; ++i) {
        float ht0 = tanh_fast(aH0[i] + bh0 + gh0[i]);
        float ht1 = tanh_fast(aH1[i] + bh1 + gh1[i]);
        float hn0 = z0[i] * hm0[i] + (1.f - z0[i]) * ht0;
        float hn1 = z1[i] * hm1[i] + (1.f - z1[i]) * ht1;
        hm0[i] = hn0; hm1[i] = hn1;
        PairU c; c.b[0] = (bf16_t)hn0; c.b[1] = (bf16_t)hn1;
        *reinterpret_cast<PairU*>(hnext + bi[i] * HID + j0) = c;  // local L2
        st_sc1(onext + bi[i] * HID + j0, hn0, hn1);               // MALL (out path)
      }
      publish_add(h_ctr);   // h_ctr -> 32*(t+2)
    }
    // write back dirty L2 so next replay (possibly different winner XCD)
    // never races two dirty copies at the MALL.
    __builtin_amdgcn_fence(__ATOMIC_RELEASE, "agent");
  } else {
    // ============ out head: 64 vocab cols; out[t-1] = h_t @ W_o + b_o ======
    const int ob  = role - NW;
    const int c0o = ob * 64;
    for (int idx = tid; idx < 64 * HID; idx += 256) {
      int n = idx & 63, k = idx >> 6;
      int g = n >> 5, m = n & 31;
      int r = g * 32 + (m & 1) * 16 + (m >> 1);
      Wbuf[r * LDSK + k] = (bf16_t)W_o[k * VOC + c0o + n];
    }
    __syncthreads();

    float bo[2][2];
#pragma unroll
    for (int g = 0; g < 2; ++g) {
      bo[g][0] = b_o[c0o + 32 * g + 2 * n16];
      bo[g][1] = b_o[c0o + 32 * g + 2 * n16 + 1];
    }
    const bf16_t* wo[2][2];
#pragma unroll
    for (int g = 0; g < 2; ++g)
#pragma unroll
      for (int h = 0; h < 2; ++h)
        wo[g][h] = &Wbuf[(g * 32 + h * 16 + n16) * LDSK + q * 8];

    unsigned* myoc = (ob == 0) ? oc0 : oc1;
    for (int t = 1; t <= TLEN; ++t) {
      wait1(h_ctr, (unsigned)(NW * (t + 1)));   // h slot t in the out-ring
      const bf16_t* hrow = oring + (t % OD) * HBUF + aoff;
      bf16x8 areg[32];
#pragma unroll
      for (int kk = 0; kk < 32; ++kk)
        areg[kk] = ld_nt16(hrow + kk * 32);
      f32x4 acc[2][2];
#pragma unroll
      for (int g = 0; g < 2; ++g)
#pragma unroll
        for (int h = 0; h < 2; ++h)
          acc[g][h] = (f32x4){0.f, 0.f, 0.f, 0.f};
#pragma unroll
      for (int kk = 0; kk < 32; ++kk) {
#pragma unroll
        for (int g = 0; g < 2; ++g) {
          bf16x8 w0 = *reinterpret_cast<const bf16x8*>(wo[g][0] + kk * 32);
          bf16x8 w1 = *reinterpret_cast<const bf16x8*>(wo[g][1] + kk * 32);
          acc[g][0] = MFMA(areg[kk], w0, acc[g][0]);
          acc[g][1] = MFMA(areg[kk], w1, acc[g][1]);
        }
      }
#pragma unroll
      for (int g = 0; g < 2; ++g) {
        const int j0 = c0o + 32 * g + 2 * n16;
#pragma unroll
        for (int i = 0; i < 4; ++i) {
          f32x2 v = {acc[g][0][i] + bo[g][0], acc[g][1][i] + bo[g][1]};
          *reinterpret_cast<f32x2*>(&out[(bi[i] * TLEN + (t - 1)) * VOC + j0]) = v;
        }
      }
      publish_val(myoc, (unsigned)t);  // NT reads retired (consumed by MFMA)
    }
  }
}

extern "C" void kernel_launch(void* const* d_in, const int* in_sizes, int n_in,
                              void* d_out, int out_size, void* d_ws, size_t ws_size,
                              hipStream_t stream) {
  const int*   X    = (const int*)d_in[0];
  const float* Wr_x = (const float*)d_in[1];
  const float* Wr_h = (const float*)d_in[2];
  const float* b_r  = (const float*)d_in[3];
  const float* Wz_x = (const float*)d_in[4];
  const float* Wz_h = (const float*)d_in[5];
  const float* b_z  = (const float*)d_in[6];
  const float* Wh_x = (const float*)d_in[7];
  const float* Wh_h = (const float*)d_in[8];
  const float* b_h  = (const float*)d_in[9];
  const float* W_o  = (const float*)d_in[10];
  const float* b_o  = (const float*)d_in[11];

  char* ws = (char*)d_ws;
  // layout: [flags 4KB | hring 2x128KB | rh 128KB | oring 16x128KB | wz 2MB]
  unsigned* flags = (unsigned*)ws;
  bf16_t*   hring = (bf16_t*)(ws + 4096);
  bf16_t*   rh_bf = (bf16_t*)(ws + 4096 + 2 * HBUF * sizeof(bf16_t));
  bf16_t*   oring = (bf16_t*)(ws + 4096 + 3 * HBUF * sizeof(bf16_t));
  bf16_t*   wz_bf = (bf16_t*)(ws + 4096 + (3 + OD) * HBUF * sizeof(bf16_t));

  // zero flags + claim state; all data buffers are written before read
  hipMemsetAsync(ws, 0, 4096, stream);

  gru_ctr<<<NBLK, 256, 0, stream>>>(
      X, Wr_x, Wr_h, b_r, Wz_x, Wz_h, b_z, Wh_x, Wh_h, b_h, W_o, b_o,
      (float*)d_out, hring, rh_bf, oring, wz_bf, flags);
}